// Round 6
// baseline (671.301 us; speedup 1.0000x reference)
//
#include <hip/hip_runtime.h>
#include <stdint.h>
#include <stddef.h>

#define D_HID 2304
#define NTOK  8192          // 4 * 2048
#define NQKV  6912          // 3 * 2304
#define WELEMS 5308416      // 2304*2304
#define SEQ_MASK 2047

typedef unsigned short u16;
typedef __bf16 bf16x8 __attribute__((ext_vector_type(8)));
typedef unsigned short ushort8 __attribute__((ext_vector_type(8)));
typedef float  f32x16 __attribute__((ext_vector_type(16)));
typedef float  f32x4  __attribute__((ext_vector_type(4)));

__device__ __forceinline__ u16 f2bf(float f) {
    unsigned int u = __builtin_bit_cast(unsigned int, f);
    u += 0x7fffu + ((u >> 16) & 1u);           // RNE
    return (u16)(u >> 16);
}
__device__ __forceinline__ float bf2f(u16 h) {
    unsigned int u = ((unsigned int)h) << 16;
    return __builtin_bit_cast(float, u);
}

__device__ __forceinline__ void gl2lds16(const void* g, void* l) {
    __builtin_amdgcn_global_load_lds(
        (const __attribute__((address_space(1))) void*)g,
        (__attribute__((address_space(3))) void*)l,
        16, 0, 0);
}

// ---------------------------------------------------------------- converts
__global__ __launch_bounds__(256) void cvt_f32_bf16(
    const float* __restrict__ src, u16* __restrict__ dst)
{
    size_t i = ((size_t)blockIdx.x * 256 + threadIdx.x) * 4;
    float4 f = *(const float4*)(src + i);
    ushort4 o = make_ushort4(f2bf(f.x), f2bf(f.y), f2bf(f.z), f2bf(f.w));
    *(ushort4*)(dst + i) = o;
}

__global__ __launch_bounds__(256) void cvt_weights(
    const float* __restrict__ wq, const float* __restrict__ wk,
    const float* __restrict__ wv, const float* __restrict__ wo,
    u16* __restrict__ dst,
    const float* __restrict__ bq, const float* __restrict__ bk,
    const float* __restrict__ bv, float* __restrict__ bqkv)
{
    int i = blockIdx.x * 256 + threadIdx.x;
    if (i < NQKV)
        bqkv[i] = (i < 2304) ? bq[i] : (i < 4608) ? bk[i - 2304] : bv[i - 4608];
    size_t base = (size_t)i * 4;
    int r = (int)(base / WELEMS);
    const float* src = (r == 0) ? wq : (r == 1) ? wk : (r == 2) ? wv : wo;
    float4 f = *(const float4*)(src + (base - (size_t)r * WELEMS));
    ushort4 o = make_ushort4(f2bf(f.x), f2bf(f.y), f2bf(f.z), f2bf(f.w));
    *(ushort4*)(dst + base) = o;
}

// ---------------------------------------------------------------- RoPE LUT
// lut[pos][2p] = cos, lut[pos][2p+1] = sin for pair p (0..1151), pos 0..2047.
__global__ __launch_bounds__(256) void rope_lut_k(float* __restrict__ lut)
{
    const float OMEGA_C = -2.0f * 13.287712379549449f / 2304.0f;
    const float INV2PI  = 0.15915494309189535f;
    const float fpos = (float)blockIdx.x;
    float* row = lut + (size_t)blockIdx.x * 2304;
    for (int p = threadIdx.x; p < 1152; p += 256) {
        float omega = exp2f((float)p * OMEGA_C);
        float rr = fpos * omega * INV2PI;
        rr -= floorf(rr);
        float sn = __builtin_amdgcn_sinf(rr);
        float cs = __builtin_amdgcn_cosf(rr);
        *(float2*)(row + 2 * p) = make_float2(cs, sn);
    }
}

// ---------------------------------------------------------------- GEMM 256^2, 2-phase register-double-buffered
// C[M,N] = A[M,K] * B[N,K]^T + bias, bf16 out. 512 thr = 8 waves (2M x 4N),
// per-wave 128x64 out via 16x16x32 MFMA. LDS = 2 K-tile buffers = 128 KiB
// (occupancy LDS-bound at 1 block/CU -> VGPRs are free; both kk-half
// fragment sets live in registers: 24 frags = 96 VGPR).
//
// 2 phases per 64-K tile, sync = 2 s_barrier + 2 lgkm0 + 1 vmcnt (was 4/3/1):
//   ph1(t): rd F1(t) s1-chunks [12 b128, lc]; STAGE B0,B1(t+2)->c;
//           32 MFMA on F0(t); vmcnt(4|0); lgkm0; sbar
//   ph2(t): rd F0(t+1) s0-chunks [12 b128, c^1]; STAGE A0,A1(t+2)->c;
//           32 MFMA on F1(t); lgkm0; sbar
// Readiness: vmcnt(4) at ph1(t) end retires A(t+1) (in-order queue there =
// [A(t+1)x4 staged ph2(t-1), B(t+2)x4 staged ph1(t)]); ph1's barrier
// globalizes it across waves before ph2's c^1 reads. Steady-state vmcnt
// never drains to 0 (B(t+2) stays in flight). Stage->use distance >= 2
// phases for every half-tile.
// Slot-overwrite ledger: B slots of c overwritten ph1(t): s0-chunk reads
// were ph2(t-1) [drained ph2 lgkm0 + sbar]; s1-chunk reads issued earlier
// in ph1(t) (ds FIFO + DMA latency, same discipline as prior rounds).
// A slots of c overwritten ph2(t): s1 reads ph1(t) [drained ph1 lgkm0 +
// sbar]; s0 reads ph2(t-1) [drained]. c^1 reads (ph2(t)) drained by ph2
// lgkm0 + sbar before ph1(t+1) stages into c^1.
// LDS 16B-chunk slot c' of row r holds global chunk c = c' ^ (r&7)
// (pre-swizzled global source, linear LDS dest, swizzled read).
__global__ __launch_bounds__(512, 2) void gemm256_bt(
    const u16* __restrict__ A, const u16* __restrict__ B,
    const float* __restrict__ bias, u16* __restrict__ Cout,
    int M, int N, int K)
{
    __shared__ __align__(16) u16 lds2[65536];   // 128 KiB

    const int tid  = threadIdx.x;
    const int lane = tid & 63;
    const int wave = tid >> 6;
    const int NT   = K >> 6;                    // 64-k tiles (36 for K=2304)
    (void)M;

    // XCD-bijective swizzle (grid % 8 == 0), bn-fast within each XCD chunk.
    const int chunk = gridDim.x >> 3;
    const int bid = (blockIdx.x & 7) * chunk + (blockIdx.x >> 3);
    const int num_bn = N >> 8;
    const int bm = bid / num_bn;
    const int bn = bid - bm * num_bn;

    // staging geometry: instr (wave, half) writes rows wave*8..+8 of a
    // 64-row stripe; lane l -> row +(l>>3), LDS slot l&7, source chunk
    // pre-swizzled = (l&7) ^ (l>>3).
    const int srow = lane >> 3;
    const u16* __restrict__ Ast = A + (size_t)(bm * 256 + wave * 8 + srow) * K
                                    + ((lane & 7) ^ srow) * 8;
    const u16* __restrict__ Bst = B + (size_t)(bn * 256 + wave * 8 + srow) * K
                                    + ((lane & 7) ^ srow) * 8;
    const size_t row64  = (size_t)64 * K;
    const size_t row128 = (size_t)128 * K;
    const int ldsW = wave * 512;

    // hsel: 0=A0 1=A1 2=B0 3=B1 of tile tt into buffer buf
#define STAGE(buf, hsel, tt) do {                                              \
    const u16* g_ = ((hsel) < 2 ? Ast : Bst)                                   \
                    + (((hsel) & 1) ? row128 : 0) + (size_t)(tt) * 64;         \
    u16* l_ = lds2 + (buf) * 32768 + (((hsel) < 2) ? 0 : 16384)                \
              + (((hsel) & 1) ? 8192 : 0) + ldsW;                              \
    gl2lds16(g_, l_);                                                          \
    gl2lds16(g_ + row64, l_ + 4096);                                           \
} while (0)

    // read geometry (16x16x32 fragments): row = mo*16 + (l&15),
    // k-chunk slot = (kk*4 + l>>4) ^ (lane&7).
    const int l15 = lane & 15, l4 = lane >> 4;
    const int aBase = (wave >> 2) * 8192 + l15 * 64;
    const int bBase = 16384 + ((wave >> 1) & 1) * 8192
                      + ((wave & 1) * 64 + l15) * 64;
    const int s0 = ((l4    ) ^ (lane & 7)) * 8;
    const int s1 = ((l4 + 4) ^ (lane & 7)) * 8;

    f32x4 acc[8][4] = {};
    bf16x8 F0B[4], F0A[8], F1B[4], F1A[8];

    // prologue: stage tiles 0 and 1 fully; vmcnt(8) retires tile 0;
    // preload F0(0).
    STAGE(0, 2, 0); STAGE(0, 3, 0); STAGE(0, 0, 0); STAGE(0, 1, 0);
    STAGE(1, 2, 1); STAGE(1, 3, 1); STAGE(1, 0, 1); STAGE(1, 1, 1);
    asm volatile("s_waitcnt vmcnt(8)" ::: "memory");
    __builtin_amdgcn_s_barrier();
#pragma unroll
    for (int n = 0; n < 4; ++n)
        F0B[n] = *(const bf16x8*)(lds2 + bBase + n * 1024 + s0);
#pragma unroll
    for (int mo = 0; mo < 8; ++mo)
        F0A[mo] = *(const bf16x8*)(lds2 + aBase + mo * 1024 + s0);

    for (int t = 0; t < NT; ++t) {
        const int cur = t & 1;
        const u16* lc = lds2 + cur * 32768;
        const u16* ln = lds2 + (cur ^ 1) * 32768;
        const bool st1 = (t + 1 < NT);
        const bool st2 = (t + 2 < NT);

        // ---- phase 1: rd F1(t); stage B(t+2); MFMA on F0; vmcnt; lgkm0
#pragma unroll
        for (int n = 0; n < 4; ++n)
            F1B[n] = *(const bf16x8*)(lc + bBase + n * 1024 + s1);
#pragma unroll
        for (int mo = 0; mo < 8; ++mo)
            F1A[mo] = *(const bf16x8*)(lc + aBase + mo * 1024 + s1);
        if (st2) { STAGE(cur, 2, t + 2); STAGE(cur, 3, t + 2); }
        __builtin_amdgcn_sched_barrier(0);
        __builtin_amdgcn_s_setprio(1);
#pragma unroll
        for (int mo = 0; mo < 8; ++mo)
#pragma unroll
            for (int n = 0; n < 4; ++n)
                acc[mo][n] = __builtin_amdgcn_mfma_f32_16x16x32_bf16(
                    F0A[mo], F0B[n], acc[mo][n], 0, 0, 0);
        __builtin_amdgcn_s_setprio(0);
        __builtin_amdgcn_sched_barrier(0);
        if (st2)      asm volatile("s_waitcnt vmcnt(4)" ::: "memory");
        else if (st1) asm volatile("s_waitcnt vmcnt(0)" ::: "memory");
        asm volatile("s_waitcnt lgkmcnt(0)" ::: "memory");
        __builtin_amdgcn_s_barrier();

        // ---- phase 2: rd F0(t+1) from c^1; stage A(t+2); MFMA on F1; lgkm0
        if (st1) {
#pragma unroll
            for (int n = 0; n < 4; ++n)
                F0B[n] = *(const bf16x8*)(ln + bBase + n * 1024 + s0);
#pragma unroll
            for (int mo = 0; mo < 8; ++mo)
                F0A[mo] = *(const bf16x8*)(ln + aBase + mo * 1024 + s0);
        }
        if (st2) { STAGE(cur, 0, t + 2); STAGE(cur, 1, t + 2); }
        __builtin_amdgcn_sched_barrier(0);
        __builtin_amdgcn_s_setprio(1);
#pragma unroll
        for (int mo = 0; mo < 8; ++mo)
#pragma unroll
            for (int n = 0; n < 4; ++n)
                acc[mo][n] = __builtin_amdgcn_mfma_f32_16x16x32_bf16(
                    F1A[mo], F1B[n], acc[mo][n], 0, 0, 0);
        __builtin_amdgcn_s_setprio(0);
        __builtin_amdgcn_sched_barrier(0);
        asm volatile("s_waitcnt lgkmcnt(0)" ::: "memory");
        __builtin_amdgcn_s_barrier();
    }
#undef STAGE

    // epilogue: C/D layout col = lane&15, row = (lane>>4)*4 + reg
    const int wm0 = (wave >> 2) * 128, wn0 = (wave & 3) * 64;
#pragma unroll
    for (int n = 0; n < 4; ++n) {
        const int gn = bn * 256 + wn0 + n * 16 + l15;
        const float bv = bias[gn];
#pragma unroll
        for (int m = 0; m < 8; ++m) {
            const int gm = bm * 256 + wm0 + m * 16 + l4 * 4;
#pragma unroll
            for (int j = 0; j < 4; ++j)
                Cout[(size_t)(gm + j) * N + gn] = f2bf(acc[m][n][j] + bv);
        }
    }
}

// ---------------------------------------------------------------- GEMM 128^2 (kept for O-proj)
template<int MODE>
__global__ __launch_bounds__(256, 3) void gemm_bt(
    const u16* __restrict__ A, const u16* __restrict__ B,
    const float* __restrict__ bias, u16* __restrict__ Cout,
    const u16* __restrict__ resid, int M, int N, int K)
{
    __shared__ __align__(16) u16 As[128 * 64];
    __shared__ __align__(16) u16 Bs[128 * 64];

    const int tid  = threadIdx.x;
    const int lane = tid & 63;
    const int wave = tid >> 6;

    const int num_bn = N >> 7;
    const int rem = blockIdx.x % (num_bn << 3);
    const int bn  = rem >> 3;
    const int bm  = ((blockIdx.x / (num_bn << 3)) << 3) + (rem & 7);

    const int srow = tid >> 3;                        // 0..31
    const int sc   = (tid & 7) ^ (srow & 7);          // swizzle key = row&7
    const u16* Ag = A + (size_t)(bm * 128 + srow) * K + sc * 8;
    const u16* Bg = B + (size_t)(bn * 128 + srow) * K + sc * 8;
    const size_t row32 = (size_t)32 * K;
    u16* asd = As + wave * 512;
    u16* bsd = Bs + wave * 512;

    const int rl = lane & 31;
    const int h  = lane >> 5;
    const int swz = rl & 7;
    const int wm = (wave >> 1) * 64;
    const int wn = (wave & 1) * 64;

    f32x16 acc[2][2] = {};

    for (int kb = 0; kb < K; kb += 64) {
        __syncthreads();
#pragma unroll
        for (int r = 0; r < 4; ++r) {
            gl2lds16(Ag + kb + r * row32, asd + r * 2048);
            gl2lds16(Bg + kb + r * row32, bsd + r * 2048);
        }
        __syncthreads();

#pragma unroll
        for (int s = 0; s < 4; ++s) {
            const int ch = ((s * 2 + h) ^ swz) * 8;
            bf16x8 a0 = *(const bf16x8*)(As + (wm      + rl) * 64 + ch);
            bf16x8 a1 = *(const bf16x8*)(As + (wm + 32 + rl) * 64 + ch);
            bf16x8 b0 = *(const bf16x8*)(Bs + (wn      + rl) * 64 + ch);
            bf16x8 b1 = *(const bf16x8*)(Bs + (wn + 32 + rl) * 64 + ch);
            acc[0][0] = __builtin_amdgcn_mfma_f32_32x32x16_bf16(a0, b0, acc[0][0], 0, 0, 0);
            acc[0][1] = __builtin_amdgcn_mfma_f32_32x32x16_bf16(a0, b1, acc[0][1], 0, 0, 0);
            acc[1][0] = __builtin_amdgcn_mfma_f32_32x32x16_bf16(a1, b0, acc[1][0], 0, 0, 0);
            acc[1][1] = __builtin_amdgcn_mfma_f32_32x32x16_bf16(a1, b1, acc[1][1], 0, 0, 0);
        }
    }

#pragma unroll
    for (int mt = 0; mt < 2; ++mt) {
#pragma unroll
        for (int nt = 0; nt < 2; ++nt) {
            const int gn = bn * 128 + wn + nt * 32 + rl;
            const float bv = bias[gn];
#pragma unroll
            for (int reg = 0; reg < 16; ++reg) {
                const int gm = bm * 128 + wm + mt * 32 +
                               (reg & 3) + 8 * (reg >> 2) + 4 * h;
                const size_t idx = (size_t)gm * N + gn;
                float v = acc[mt][nt][reg] + bv;
                if constexpr (MODE == 1) v += bf2f(resid[idx]);
                Cout[idx] = f2bf(v);
            }
        }
    }
}

// ---------------------------------------------------------------- attention (wave-per-token, MFMA)
__device__ __forceinline__ ushort8 rope8(ushort8 v, float4 t0, float4 t1) {
    ushort8 o;
    float x0, x1;
    x0 = bf2f(v[0]); x1 = bf2f(v[1]);
    o[0] = f2bf(t0.x * x0 - t0.y * x1); o[1] = f2bf(t0.y * x0 + t0.x * x1);
    x0 = bf2f(v[2]); x1 = bf2f(v[3]);
    o[2] = f2bf(t0.z * x0 - t0.w * x1); o[3] = f2bf(t0.w * x0 + t0.z * x1);
    x0 = bf2f(v[4]); x1 = bf2f(v[5]);
    o[4] = f2bf(t1.x * x0 - t1.y * x1); o[5] = f2bf(t1.y * x0 + t1.x * x1);
    x0 = bf2f(v[6]); x1 = bf2f(v[7]);
    o[6] = f2bf(t1.z * x0 - t1.w * x1); o[7] = f2bf(t1.w * x0 + t1.z * x1);
    return o;
}

__global__ __launch_bounds__(512) void attn_mfma(
    const u16* __restrict__ QKV, const float* __restrict__ lut,
    u16* __restrict__ Aout)
{
    __shared__ __align__(16) u16 smem[8 * 2688];   // 43008 B
    const int tid  = threadIdx.x;
    const int lane = tid & 63;
    const int wave = tid >> 6;
    const int t    = blockIdx.x * 8 + wave;
    const int l15  = lane & 15, l4 = lane >> 4;

    u16* VT = smem + wave * 2688;          // [144][16] u16 (rows 32B)
    u16* WT = VT + 2304;                   // [16][24]  u16 (rows 48B)

    const u16* row = QKV + (size_t)t * NQKV;
    const float* lutrow = lut + (size_t)(t & SEQ_MASK) * 2304;

    // ---- q/k fragments (+RoPE) straight from global
    bf16x8 qf[5], kf[5];
#pragma unroll
    for (int kc = 0; kc < 5; ++kc) {
        const int dbase = kc * 32 + l4 * 8;
        ushort8 qv = {}, kv = {};
        if (dbase < 144) {
            qv = *(const ushort8*)(row + l15 * 144 + dbase);
            kv = *(const ushort8*)(row + 2304 + l15 * 144 + dbase);
            const float* lp = lutrow + l15 * 144 + dbase;   // = 2*pair_idx
            float4 c0 = *(const float4*)(lp);
            float4 c1 = *(const float4*)(lp + 4);
            qv = rope8(qv, c0, c1);
            kv = rope8(kv, c0, c1);
        }
        qf[kc] = __builtin_bit_cast(bf16x8, qv);
        kf[kc] = __builtin_bit_cast(bf16x8, kv);
    }

    // ---- V -> VT (transposed) for the O-step B-fragments
#pragma unroll
    for (int kc = 0; kc < 5; ++kc) {
        const int dbase = kc * 32 + l4 * 8;
        if (dbase < 144) {
            ushort8 vv = *(const ushort8*)(row + 4608 + l15 * 144 + dbase);
#pragma unroll
            for (int j = 0; j < 8; ++j)
                VT[(dbase + j) * 16 + l15] = vv[j];
        }
    }

    // ---- S = Q K^T (fp32 accum)
    f32x4 S = {};
#pragma unroll
    for (int kc = 0; kc < 5; ++kc)
        S = __builtin_amdgcn_mfma_f32_16x16x32_bf16(qf[kc], kf[kc], S, 0, 0, 0);

    // ---- softmax over m (across the 16-lane group), one row n per reg
#pragma unroll
    for (int r = 0; r < 4; ++r) {
        float s = S[r] * (1.0f / 12.0f);
        float mx = s;
#pragma unroll
        for (int off = 8; off >= 1; off >>= 1) mx = fmaxf(mx, __shfl_xor(mx, off));
        float e = __expf(s - mx);
        float sum = e;
#pragma unroll
        for (int off = 8; off >= 1; off >>= 1) sum += __shfl_xor(sum, off);
        WT[(l4 * 4 + r) * 24 + l15] = f2bf(e / sum);
    }

    // ---- O = W V : A-frag W[n=l15][m=l4*8+j] (l4<2, else zero)
    bf16x8 wA = {};
    if (l4 < 2) wA = *(const bf16x8*)(WT + l15 * 24 + l4 * 8);

    u16* orow = Aout + (size_t)t * D_HID;
#pragma unroll
    for (int db = 0; db < 9; ++db) {
        bf16x8 vB = {};
        if (l4 < 2) vB = *(const bf16x8*)(VT + (db * 16 + l15) * 16 + l4 * 8);
        f32x4 o = {};
        o = __builtin_amdgcn_mfma_f32_16x16x32_bf16(wA, vB, o, 0, 0, 0);
#pragma unroll
        for (int r = 0; r < 4; ++r)
            orow[(l4 * 4 + r) * 144 + db * 16 + l15] = f2bf(o[r]);
    }
}

// ---------------------------------------------------------------- layernorm
__global__ __launch_bounds__(256) void ln_kernel(
    const u16* __restrict__ Y, const float* __restrict__ g,
    const float* __restrict__ b, float* __restrict__ out)
{
    const int tid  = threadIdx.x;
    const u16* y = Y + (size_t)blockIdx.x * D_HID;
    uint4 raw = *(const uint4*)(y + tid * 8);
    u16 extra = y[2048 + tid];
    float v[9];
    v[0] = bf2f(raw.x & 0xffff); v[1] = bf2f(raw.x >> 16);
    v[2] = bf2f(raw.y & 0xffff); v[3] = bf2f(raw.y >> 16);
    v[4] = bf2f(raw.z & 0xffff); v[5] = bf2f(raw.z >> 16);
    v[6] = bf2f(raw.w & 0xffff); v[7] = bf2f(raw.w >> 16);
    v[8] = bf2f(extra);
    float s = 0.f, s2 = 0.f;
#pragma unroll
    for (int r = 0; r < 9; ++r) { s += v[r]; s2 += v[r] * v[r]; }
#pragma unroll
    for (int off = 32; off >= 1; off >>= 1) {
        s  += __shfl_xor(s, off);
        s2 += __shfl_xor(s2, off);
    }
    __shared__ float red[8];
    const int wave = tid >> 6;
    if ((tid & 63) == 0) { red[wave] = s; red[4 + wave] = s2; }
    __syncthreads();
    s  = red[0] + red[1] + red[2] + red[3];
    s2 = red[4] + red[5] + red[6] + red[7];
    const float inv_n = 1.0f / 2304.0f;
    float mu  = s * inv_n;
    float var = fmaxf(s2 * inv_n - mu * mu, 0.f);
    float inv = rsqrtf(var + 1e-5f);
    float* orow = out + (size_t)blockIdx.x * D_HID;
    float4 g0 = *(const float4*)(g + tid * 8);
    float4 g1 = *(const float4*)(g + tid * 8 + 4);
    float4 b0 = *(const float4*)(b + tid * 8);
    float4 b1 = *(const float4*)(b + tid * 8 + 4);
    float4 o0, o1;
    o0.x = (v[0] - mu) * inv * g0.x + b0.x;
    o0.y = (v[1] - mu) * inv * g0.y + b0.y;
    o0.z = (v[2] - mu) * inv * g0.z + b0.z;
    o0.w = (v[3] - mu) * inv * g0.w + b0.w;
    o1.x = (v[4] - mu) * inv * g1.x + b1.x;
    o1.y = (v[5] - mu) * inv * g1.y + b1.y;
    o1.z = (v[6] - mu) * inv * g1.z + b1.z;
    o1.w = (v[7] - mu) * inv * g1.w + b1.w;
    *(float4*)(orow + tid * 8)     = o0;
    *(float4*)(orow + tid * 8 + 4) = o1;
    orow[2048 + tid] = (v[8] - mu) * inv * g[2048 + tid] + b[2048 + tid];
}

// ---------------------------------------------------------------- launch
extern "C" void kernel_launch(void* const* d_in, const int* in_sizes, int n_in,
                              void* d_out, int out_size, void* d_ws, size_t ws_size,
                              hipStream_t stream)
{
    const float* x   = (const float*)d_in[0];
    const float* wq  = (const float*)d_in[1];
    const float* bq  = (const float*)d_in[2];
    const float* wk  = (const float*)d_in[3];
    const float* bk  = (const float*)d_in[4];
    const float* wv  = (const float*)d_in[5];
    const float* bv  = (const float*)d_in[6];
    const float* wo  = (const float*)d_in[7];
    const float* bo  = (const float*)d_in[8];
    const float* lng = (const float*)d_in[9];
    const float* lnb = (const float*)d_in[10];

    char* ws = (char*)d_ws;
    size_t off = 0;
    auto alloc = [&](size_t bytes) {
        void* p = ws + off;
        off += (bytes + 255) & ~(size_t)255;
        return p;
    };
    u16*   xb   = (u16*)alloc((size_t)NTOK * D_HID * 2);
    u16*   wqkv = (u16*)alloc((size_t)(NQKV + D_HID) * D_HID * 2);
    u16*   wob  = wqkv + (size_t)NQKV * D_HID;
    float* bqkv = (float*)alloc((size_t)NQKV * 4);
    u16*   qkv  = (u16*)alloc((size_t)NTOK * NQKV * 2);
    u16*   aout = (u16*)alloc((size_t)NTOK * D_HID * 2);
    float* lutw = (float*)alloc((size_t)2048 * 2304 * 4);
    u16*   ybuf = qkv;  // QKV dead after attention; reuse for bf16 y

    rope_lut_k<<<2048, 256, 0, stream>>>(lutw);
    cvt_f32_bf16<<<NTOK * D_HID / 1024, 256, 0, stream>>>(x, xb);
    cvt_weights<<<4 * WELEMS / 1024, 256, 0, stream>>>(wq, wk, wv, wo, wqkv,
                                                       bq, bk, bv, bqkv);
    gemm256_bt<<<(NTOK / 256) * (NQKV / 256), 512, 0, stream>>>(
        xb, wqkv, bqkv, qkv, NTOK, NQKV, D_HID);
    attn_mfma<<<NTOK / 8, 512, 0, stream>>>(qkv, lutw, aout);
    gemm_bt<1><<<(D_HID / 128) * (NTOK / 128), 256, 0, stream>>>(
        aout, wob, bo, ybuf, xb, NTOK, D_HID, D_HID);
    ln_kernel<<<NTOK, 256, 0, stream>>>(ybuf, lng, lnb, (float*)d_out);
}